// Round 1
// baseline (300.296 us; speedup 1.0000x reference)
//
#include <hip/hip_runtime.h>
#include <stdint.h>

#define TOKENS 8192
#define INF    4096
#define OUTF   4096
#define RANK   256

typedef __attribute__((ext_vector_type(8))) short bf16x8;
typedef __attribute__((ext_vector_type(4))) float f32x4;

__device__ __forceinline__ unsigned short f2bf(float f) {
    union { float f; unsigned int u; } v; v.f = f;
    unsigned int r = v.u + 0x7FFFu + ((v.u >> 16) & 1u);   // RNE
    return (unsigned short)(r >> 16);
}

__device__ __forceinline__ void gl_lds16(const void* g, void* l) {
    __builtin_amdgcn_global_load_lds(
        (const __attribute__((address_space(1))) unsigned int*)g,
        (__attribute__((address_space(3))) unsigned int*)l, 16, 0, 0);
}

// ---------------- fp32 -> bf16 convert (V, U) ----------------
__global__ void cvt4(const float4* __restrict__ in, ushort4* __restrict__ out) {
    int i = blockIdx.x * blockDim.x + threadIdx.x;
    float4 v = in[i];
    ushort4 o;
    o.x = f2bf(v.x); o.y = f2bf(v.y); o.z = f2bf(v.z); o.w = f2bf(v.w);
    out[i] = o;
}

// ---------------- GEMM1: T[8192,256] = x @ V^T (bf16 MFMA) ----------------
// BM=32 tokens, BN=256 (full rank -> x read exactly once), BK=128.
// 512 thr (8 waves), grid = 256 blocks (1/CU). Wave tile: 32 rank x 32 tok.
// V-operand: global->register, double-buffered (V is 2MB, L2-resident;
// rank rows are wave-private so LDS staging of V buys nothing).
// x-tile: fp32->bf16 pack through LDS, double-buffered, ONE barrier/K-tile.
#define G1_BM 32
#define G1_BK 128
#define A1_STR 136   // 128+8 pad: bank-conflict-free frag reads, 16B-aligned rows

__device__ __forceinline__ void g1_loadV(bf16x8 (&V)[2][4],
                                         const unsigned short* vr0,
                                         const unsigned short* vr1,
                                         int kk, int quad) {
    #pragma unroll
    for (int ks = 0; ks < 4; ++ks) {
        V[0][ks] = *(const bf16x8*)(vr0 + kk + ks * 32 + quad * 8);
        V[1][ks] = *(const bf16x8*)(vr1 + kk + ks * 32 + quad * 8);
    }
}

__device__ __forceinline__ void g1_compute(f32x4 (&acc)[2][2],
                                           const bf16x8 (&V)[2][4],
                                           const unsigned short* ax,
                                           int l15, int quad) {
    #pragma unroll
    for (int ks = 0; ks < 4; ++ks) {
        bf16x8 b0 = *(const bf16x8*)(ax + l15 * A1_STR + ks * 32 + quad * 8);
        bf16x8 b1 = *(const bf16x8*)(ax + (16 + l15) * A1_STR + ks * 32 + quad * 8);
        acc[0][0] = __builtin_amdgcn_mfma_f32_16x16x32_bf16(V[0][ks], b0, acc[0][0], 0, 0, 0);
        acc[0][1] = __builtin_amdgcn_mfma_f32_16x16x32_bf16(V[0][ks], b1, acc[0][1], 0, 0, 0);
        acc[1][0] = __builtin_amdgcn_mfma_f32_16x16x32_bf16(V[1][ks], b0, acc[1][0], 0, 0, 0);
        acc[1][1] = __builtin_amdgcn_mfma_f32_16x16x32_bf16(V[1][ks], b1, acc[1][1], 0, 0, 0);
    }
}

__device__ __forceinline__ void g1_pack(float4 a, float4 b, unsigned short* dst) {
    union { bf16x8 v; unsigned short s[8]; } pk;
    pk.s[0] = f2bf(a.x); pk.s[1] = f2bf(a.y);
    pk.s[2] = f2bf(a.z); pk.s[3] = f2bf(a.w);
    pk.s[4] = f2bf(b.x); pk.s[5] = f2bf(b.y);
    pk.s[6] = f2bf(b.z); pk.s[7] = f2bf(b.w);
    *(bf16x8*)dst = pk.v;
}

__global__ __launch_bounds__(512) void gemm1(const float* __restrict__ x,
                                             const unsigned short* __restrict__ Vb,
                                             unsigned short* __restrict__ T) {
    __shared__ __align__(16) unsigned short Ax[2][G1_BM * A1_STR];  // 2 x 8.5 KB

    const int tid  = threadIdx.x;
    const int lane = tid & 63;
    const int wid  = tid >> 6;            // 0..7 -> rank rows wid*32..wid*32+31
    const int m0   = blockIdx.x * G1_BM;  // token base
    const int l15  = lane & 15;
    const int quad = lane >> 4;

    // x staging: thread -> (row 0..31, 8-elem k segment 0..15)
    const int arow = tid >> 4;
    const int aseg = tid & 15;
    const float* xp = x + (size_t)(m0 + arow) * INF + aseg * 8;
    unsigned short* aw0 = &Ax[0][arow * A1_STR + aseg * 8];
    unsigned short* aw1 = &Ax[1][arow * A1_STR + aseg * 8];

    // V fragment row pointers (wave-private rank rows)
    const unsigned short* vr0 = Vb + (size_t)(wid * 32 + l15) * INF;
    const unsigned short* vr1 = vr0 + (size_t)16 * INF;

    f32x4 acc[2][2];
    #pragma unroll
    for (int i = 0; i < 2; ++i)
        #pragma unroll
        for (int j = 0; j < 2; ++j) acc[i][j] = (f32x4){0.f, 0.f, 0.f, 0.f};

    bf16x8 VA[2][4], VB[2][4];

    // prologue: stage x tile 0 to buf0, load V tile 0 to VA
    float4 xr0 = *(const float4*)(xp);
    float4 xr1 = *(const float4*)(xp + 4);
    g1_pack(xr0, xr1, aw0);
    g1_loadV(VA, vr0, vr1, 0, quad);

    for (int kt = 0; kt < 32; kt += 2) {
        const int k1 = (kt + 1) * G1_BK;
        const int k2 = (kt + 2 < 32 ? kt + 2 : 31) * G1_BK;  // clamp: no OOB on last iter

        __syncthreads();   // buf0 (tile kt) visible; prev readers of buf1 done
        xr0 = *(const float4*)(xp + k1);
        xr1 = *(const float4*)(xp + k1 + 4);
        g1_loadV(VB, vr0, vr1, k1, quad);          // prefetch V for tile kt+1
        g1_compute(acc, VA, &Ax[0][0], l15, quad); // compute tile kt
        g1_pack(xr0, xr1, aw1);                    // write x tile kt+1

        __syncthreads();   // buf1 (tile kt+1) visible; prev readers of buf0 done
        xr0 = *(const float4*)(xp + k2);
        xr1 = *(const float4*)(xp + k2 + 4);
        g1_loadV(VA, vr0, vr1, k2, quad);          // prefetch V for tile kt+2
        g1_compute(acc, VB, &Ax[1][0], l15, quad); // compute tile kt+1
        g1_pack(xr0, xr1, aw0);                    // write x tile kt+2
    }

    // epilogue: D row = rank offset (quad*4+r), col = token (l15)
    #pragma unroll
    for (int mv = 0; mv < 2; ++mv) {
        #pragma unroll
        for (int mx = 0; mx < 2; ++mx) {
            int m = m0 + mx * 16 + l15;
            int n = wid * 32 + mv * 16 + quad * 4;
            ushort4 o;
            o.x = f2bf(acc[mv][mx][0]); o.y = f2bf(acc[mv][mx][1]);
            o.z = f2bf(acc[mv][mx][2]); o.w = f2bf(acc[mv][mx][3]);
            *(ushort4*)&T[(size_t)m * RANK + n] = o;
        }
    }
}

// ---------------- GEMM2: out = T @ U^T + bias (bf16 MFMA, fp32 out) -------
// BM=128 tokens, BN=128 outf, BK=64, K=256 (4 iters), 256 thr, grid 32x64.
// Double-buffered LDS staging: ONE barrier per K-tile, prefetch overlaps MFMA.
#define G2_BM 128
#define G2_BN 128
#define G2_BK 64

__device__ __forceinline__ void g2_stage(unsigned short (&Tl)[2][G2_BM * G2_BK],
                                         unsigned short (&Ul)[2][G2_BN * G2_BK],
                                         int b, int kk,
                                         const unsigned short* Tb,
                                         const unsigned short* Ub,
                                         int m0, int n0, int wid, int lrow, int cf) {
    #pragma unroll
    for (int j = 0; j < 4; ++j) {
        int r0 = wid * 32 + j * 8;
        gl_lds16(Tb + (size_t)(m0 + r0 + lrow) * RANK + kk + cf * 8, &Tl[b][r0 * G2_BK]);
        gl_lds16(Ub + (size_t)(n0 + r0 + lrow) * RANK + kk + cf * 8, &Ul[b][r0 * G2_BK]);
    }
}

__global__ __launch_bounds__(256) void gemm2(const unsigned short* __restrict__ Tb,
                                             const unsigned short* __restrict__ Ub,
                                             const float* __restrict__ bias,
                                             float* __restrict__ out) {
    __shared__ __align__(16) unsigned short Tlds[2][G2_BM * G2_BK]; // 2 x 16 KB
    __shared__ __align__(16) unsigned short Ulds[2][G2_BN * G2_BK]; // 2 x 16 KB

    const int tid  = threadIdx.x;
    const int lane = tid & 63;
    const int wid  = tid >> 6;
    const int wy   = wid >> 1, wx = wid & 1;     // token half / outf half
    const int m0   = blockIdx.y * G2_BM;
    const int n0   = blockIdx.x * G2_BN;
    const int l15  = lane & 15, quad = lane >> 4;
    const int lrow = lane >> 3;                  // 0..7 (8 rows per instr)
    const int cf   = (lane & 7) ^ lrow;          // swizzled fetch chunk

    f32x4 acc[4][4];   // [nt][mt]
    #pragma unroll
    for (int i = 0; i < 4; i++)
        #pragma unroll
        for (int j = 0; j < 4; j++) acc[i][j] = (f32x4){0.f, 0.f, 0.f, 0.f};

    // bias prefetch (independent; hides epilogue latency)
    float4 bv[4];
    #pragma unroll
    for (int nt = 0; nt < 4; ++nt)
        bv[nt] = *(const float4*)&bias[n0 + wx * 64 + nt * 16 + quad * 4];

    // stage tile 0 into buf0
    g2_stage(Tlds, Ulds, 0, 0, Tb, Ub, m0, n0, wid, lrow, cf);

    #pragma unroll
    for (int t = 0; t < 4; ++t) {
        __syncthreads();  // drains vmcnt: buf[t&1] ready; prev readers of buf[(t+1)&1] done
        if (t < 3)
            g2_stage(Tlds, Ulds, (t + 1) & 1, (t + 1) * G2_BK,
                     Tb, Ub, m0, n0, wid, lrow, cf);   // prefetch next tile
        const int b = t & 1;
        #pragma unroll
        for (int ks = 0; ks < 2; ++ks) {
            bf16x8 aU[4], bT[4];
            #pragma unroll
            for (int tt = 0; tt < 4; ++tt) {
                int ur = wx * 64 + tt * 16 + l15;
                int up = (ks * 4 + quad) ^ (ur & 7);
                aU[tt] = *(const bf16x8*)&Ulds[b][ur * G2_BK + up * 8];
                int tr = wy * 64 + tt * 16 + l15;
                int tp = (ks * 4 + quad) ^ (tr & 7);
                bT[tt] = *(const bf16x8*)&Tlds[b][tr * G2_BK + tp * 8];
            }
            #pragma unroll
            for (int nt = 0; nt < 4; ++nt)
                #pragma unroll
                for (int mt = 0; mt < 4; ++mt)
                    acc[nt][mt] = __builtin_amdgcn_mfma_f32_16x16x32_bf16(
                        aU[nt], bT[mt], acc[nt][mt], 0, 0, 0);
        }
    }

    // epilogue: D row = outf offset (quad*4+r), col = token (l15)
    #pragma unroll
    for (int nt = 0; nt < 4; ++nt) {
        int n_base = n0 + wx * 64 + nt * 16 + quad * 4;
        #pragma unroll
        for (int mt = 0; mt < 4; ++mt) {
            int m = m0 + wy * 64 + mt * 16 + l15;
            float4 v;
            v.x = acc[nt][mt][0] + bv[nt].x;
            v.y = acc[nt][mt][1] + bv[nt].y;
            v.z = acc[nt][mt][2] + bv[nt].z;
            v.w = acc[nt][mt][3] + bv[nt].w;
            *(float4*)&out[(size_t)m * OUTF + n_base] = v;
        }
    }
}

extern "C" void kernel_launch(void* const* d_in, const int* in_sizes, int n_in,
                              void* d_out, int out_size, void* d_ws, size_t ws_size,
                              hipStream_t stream) {
    const float* x    = (const float*)d_in[0];
    const float* U    = (const float*)d_in[1];
    const float* V    = (const float*)d_in[2];
    const float* bias = (const float*)d_in[3];
    float* out = (float*)d_out;

    // ws layout: Vb (2MB) | Ub (2MB) | Tb (4MB)  => 8 MB total
    unsigned short* Vb = (unsigned short*)d_ws;
    unsigned short* Ub = Vb + (size_t)RANK * INF;
    unsigned short* Tb = Ub + (size_t)OUTF * RANK;

    cvt4<<<(RANK * INF / 4) / 256, 256, 0, stream>>>((const float4*)V, (ushort4*)Vb);
    cvt4<<<(OUTF * RANK / 4) / 256, 256, 0, stream>>>((const float4*)U, (ushort4*)Ub);
    gemm1<<<TOKENS / G1_BM, 512, 0, stream>>>(x, Vb, Tb);
    gemm2<<<dim3(OUTF / G2_BN, TOKENS / G2_BM), 256, 0, stream>>>(Tb, Ub, bias, out);
}

// Round 3
// 284.174 us; speedup vs baseline: 1.0567x; 1.0567x over previous
//
#include <hip/hip_runtime.h>
#include <stdint.h>

#define TOKENS 8192
#define INF    4096
#define OUTF   4096
#define RANK   256

typedef __attribute__((ext_vector_type(8))) short bf16x8;
typedef __attribute__((ext_vector_type(4))) float f32x4;

__device__ __forceinline__ unsigned short f2bf(float f) {
    union { float f; unsigned int u; } v; v.f = f;
    unsigned int r = v.u + 0x7FFFu + ((v.u >> 16) & 1u);   // RNE
    return (unsigned short)(r >> 16);
}

__device__ __forceinline__ void gl_lds16(const void* g, void* l) {
    __builtin_amdgcn_global_load_lds(
        (const __attribute__((address_space(1))) unsigned int*)g,
        (__attribute__((address_space(3))) unsigned int*)l, 16, 0, 0);
}

// ---------------- fp32 -> bf16 convert (V then U, one launch) ----------------
__global__ void cvt4(const float4* __restrict__ va, ushort4* __restrict__ oa, int na,
                     const float4* __restrict__ vb, ushort4* __restrict__ ob) {
    int i = blockIdx.x * blockDim.x + threadIdx.x;
    float4 v;
    if (i < na) v = va[i]; else v = vb[i - na];
    ushort4 o;
    o.x = f2bf(v.x); o.y = f2bf(v.y); o.z = f2bf(v.z); o.w = f2bf(v.w);
    if (i < na) oa[i] = o; else ob[i - na] = o;
}

// ---------------- GEMM1: T[8192,256] = x @ V^T (bf16 MFMA) ----------------
// BM=32 tokens, BN=256 (full rank -> x read exactly once), BK=128.
// 512 thr (8 waves), grid = 256 blocks. Wave tile: 32 rank x 32 tok.
// V staged via global_load_lds (un-sinkable async DMA, barrier-ordered),
// XOR-swizzled chunks, double-buffered 2x64KB. x: fp32 load -> bf16 pack ->
// ds_write, double-buffered 2x8.5KB. ONE barrier per K-tile.
// Round-1 lesson: register-prefetch of V was sunk by the compiler
// (VGPR_Count=44 < pipeline state) -> full L2 latency serialized per MFMA.
#define G1_BM 32
#define G1_BK 128
#define A1_STR 136   // 128+8 pad

__device__ __forceinline__ void g1_stageV(const unsigned short* __restrict__ Vb,
                                          unsigned short* vdst, int kk,
                                          int wid, int lane) {
    // wave stages V rows wid*32..+31 of this BK slice; dest linear, source
    // chunk-XOR-permuted so a swizzled read sees global order (rule 21).
    #pragma unroll
    for (int j = 0; j < 8; ++j) {
        int r0  = wid * 32 + j * 4;
        int row = r0 + (lane >> 4);
        int c   = (lane & 15) ^ (row & 7);
        gl_lds16(Vb + (size_t)row * INF + kk + c * 8, vdst + r0 * G1_BK);
    }
}

__device__ __forceinline__ void g1_pack(float4 a, float4 b, unsigned short* dst) {
    union { bf16x8 v; unsigned short s[8]; } pk;
    pk.s[0] = f2bf(a.x); pk.s[1] = f2bf(a.y);
    pk.s[2] = f2bf(a.z); pk.s[3] = f2bf(a.w);
    pk.s[4] = f2bf(b.x); pk.s[5] = f2bf(b.y);
    pk.s[6] = f2bf(b.z); pk.s[7] = f2bf(b.w);
    *(bf16x8*)dst = pk.v;
}

__device__ __forceinline__ void g1_compute(f32x4 (&acc)[2][2],
                                           const unsigned short* vbuf,
                                           const unsigned short* abuf,
                                           int l15, int quad, int wid) {
    const int rr0 = wid * 32 + l15;
    const int sw  = l15 & 7;
    #pragma unroll
    for (int ks = 0; ks < 4; ++ks) {
        int p = ((ks * 4 + quad) ^ sw) * 8;
        bf16x8 v0 = *(const bf16x8*)&vbuf[rr0 * G1_BK + p];
        bf16x8 v1 = *(const bf16x8*)&vbuf[(rr0 + 16) * G1_BK + p];
        bf16x8 b0 = *(const bf16x8*)&abuf[l15 * A1_STR + ks * 32 + quad * 8];
        bf16x8 b1 = *(const bf16x8*)&abuf[(16 + l15) * A1_STR + ks * 32 + quad * 8];
        acc[0][0] = __builtin_amdgcn_mfma_f32_16x16x32_bf16(v0, b0, acc[0][0], 0, 0, 0);
        acc[0][1] = __builtin_amdgcn_mfma_f32_16x16x32_bf16(v0, b1, acc[0][1], 0, 0, 0);
        acc[1][0] = __builtin_amdgcn_mfma_f32_16x16x32_bf16(v1, b0, acc[1][0], 0, 0, 0);
        acc[1][1] = __builtin_amdgcn_mfma_f32_16x16x32_bf16(v1, b1, acc[1][1], 0, 0, 0);
    }
}

__global__ __launch_bounds__(512) void gemm1(const float* __restrict__ x,
                                             const unsigned short* __restrict__ Vb,
                                             unsigned short* __restrict__ T) {
    __shared__ __align__(16) unsigned short V0[RANK * G1_BK];   // 64 KB
    __shared__ __align__(16) unsigned short V1[RANK * G1_BK];   // 64 KB
    __shared__ __align__(16) unsigned short A0[G1_BM * A1_STR]; // 8.5 KB
    __shared__ __align__(16) unsigned short A1[G1_BM * A1_STR]; // 8.5 KB

    const int tid  = threadIdx.x;
    const int lane = tid & 63;
    const int wid  = tid >> 6;            // 0..7 -> rank rows wid*32..+31
    const int m0   = blockIdx.x * G1_BM;  // token base
    const int l15  = lane & 15;
    const int quad = lane >> 4;

    // x staging: thread -> (row 0..31, 8-elem k segment 0..15)
    const int arow = tid >> 4;
    const int aseg = tid & 15;
    const float* xp = x + (size_t)(m0 + arow) * INF + aseg * 8;
    unsigned short* aw0 = &A0[arow * A1_STR + aseg * 8];
    unsigned short* aw1 = &A1[arow * A1_STR + aseg * 8];

    f32x4 acc[2][2];
    #pragma unroll
    for (int i = 0; i < 2; ++i)
        #pragma unroll
        for (int j = 0; j < 2; ++j) acc[i][j] = (f32x4){0.f, 0.f, 0.f, 0.f};

    // prologue: stage tile 0
    g1_stageV(Vb, V0, 0, wid, lane);
    float4 xr0 = *(const float4*)(xp);
    float4 xr1 = *(const float4*)(xp + 4);
    g1_pack(xr0, xr1, aw0);

    for (int t = 0; t < 30; t += 2) {
        __syncthreads();   // V0/A0 (tile t) ready; readers of V1/A1 done
        g1_stageV(Vb, V1, (t + 1) * G1_BK, wid, lane);
        xr0 = *(const float4*)(xp + (t + 1) * G1_BK);
        xr1 = *(const float4*)(xp + (t + 1) * G1_BK + 4);
        g1_compute(acc, V0, A0, l15, quad, wid);
        g1_pack(xr0, xr1, aw1);

        __syncthreads();   // V1/A1 (tile t+1) ready; readers of V0/A0 done
        g1_stageV(Vb, V0, (t + 2) * G1_BK, wid, lane);
        xr0 = *(const float4*)(xp + (t + 2) * G1_BK);
        xr1 = *(const float4*)(xp + (t + 2) * G1_BK + 4);
        g1_compute(acc, V1, A1, l15, quad, wid);
        g1_pack(xr0, xr1, aw0);
    }
    // tiles 30 (in V0/A0) and 31 (stage now)
    __syncthreads();
    g1_stageV(Vb, V1, 31 * G1_BK, wid, lane);
    xr0 = *(const float4*)(xp + 31 * G1_BK);
    xr1 = *(const float4*)(xp + 31 * G1_BK + 4);
    g1_compute(acc, V0, A0, l15, quad, wid);
    g1_pack(xr0, xr1, aw1);
    __syncthreads();
    g1_compute(acc, V1, A1, l15, quad, wid);

    // epilogue: D row = rank offset (quad*4+r), col = token (l15)
    #pragma unroll
    for (int mv = 0; mv < 2; ++mv) {
        #pragma unroll
        for (int mx = 0; mx < 2; ++mx) {
            int m = m0 + mx * 16 + l15;
            int n = wid * 32 + mv * 16 + quad * 4;
            ushort4 o;
            o.x = f2bf(acc[mv][mx][0]); o.y = f2bf(acc[mv][mx][1]);
            o.z = f2bf(acc[mv][mx][2]); o.w = f2bf(acc[mv][mx][3]);
            *(ushort4*)&T[(size_t)m * RANK + n] = o;
        }
    }
}

// ---------------- GEMM2: out = T @ U^T + bias (bf16 MFMA, fp32 out) -------
// BM=128 tokens, BN=128 outf, BK=64, K=256 (4 iters), 256 thr, grid 32x64.
// Double-buffered LDS staging: ONE barrier per K-tile, prefetch overlaps MFMA.
#define G2_BM 128
#define G2_BN 128
#define G2_BK 64

__device__ __forceinline__ void g2_stage(unsigned short (&Tl)[2][G2_BM * G2_BK],
                                         unsigned short (&Ul)[2][G2_BN * G2_BK],
                                         int b, int kk,
                                         const unsigned short* Tb,
                                         const unsigned short* Ub,
                                         int m0, int n0, int wid, int lrow, int cf) {
    #pragma unroll
    for (int j = 0; j < 4; ++j) {
        int r0 = wid * 32 + j * 8;
        gl_lds16(Tb + (size_t)(m0 + r0 + lrow) * RANK + kk + cf * 8, &Tl[b][r0 * G2_BK]);
        gl_lds16(Ub + (size_t)(n0 + r0 + lrow) * RANK + kk + cf * 8, &Ul[b][r0 * G2_BK]);
    }
}

__global__ __launch_bounds__(256) void gemm2(const unsigned short* __restrict__ Tb,
                                             const unsigned short* __restrict__ Ub,
                                             const float* __restrict__ bias,
                                             float* __restrict__ out) {
    __shared__ __align__(16) unsigned short Tlds[2][G2_BM * G2_BK]; // 2 x 16 KB
    __shared__ __align__(16) unsigned short Ulds[2][G2_BN * G2_BK]; // 2 x 16 KB

    const int tid  = threadIdx.x;
    const int lane = tid & 63;
    const int wid  = tid >> 6;
    const int wy   = wid >> 1, wx = wid & 1;     // token half / outf half
    const int m0   = blockIdx.y * G2_BM;
    const int n0   = blockIdx.x * G2_BN;
    const int l15  = lane & 15, quad = lane >> 4;
    const int lrow = lane >> 3;                  // 0..7 (8 rows per instr)
    const int cf   = (lane & 7) ^ lrow;          // swizzled fetch chunk

    f32x4 acc[4][4];   // [nt][mt]
    #pragma unroll
    for (int i = 0; i < 4; i++)
        #pragma unroll
        for (int j = 0; j < 4; j++) acc[i][j] = (f32x4){0.f, 0.f, 0.f, 0.f};

    // bias prefetch (independent; hides epilogue latency)
    float4 bv[4];
    #pragma unroll
    for (int nt = 0; nt < 4; ++nt)
        bv[nt] = *(const float4*)&bias[n0 + wx * 64 + nt * 16 + quad * 4];

    // stage tile 0 into buf0
    g2_stage(Tlds, Ulds, 0, 0, Tb, Ub, m0, n0, wid, lrow, cf);

    #pragma unroll
    for (int t = 0; t < 4; ++t) {
        __syncthreads();  // drains vmcnt: buf[t&1] ready; readers of other buf done
        if (t < 3)
            g2_stage(Tlds, Ulds, (t + 1) & 1, (t + 1) * G2_BK,
                     Tb, Ub, m0, n0, wid, lrow, cf);   // prefetch next tile
        const int b = t & 1;
        #pragma unroll
        for (int ks = 0; ks < 2; ++ks) {
            bf16x8 aU[4], bT[4];
            #pragma unroll
            for (int tt = 0; tt < 4; ++tt) {
                int ur = wx * 64 + tt * 16 + l15;
                int up = (ks * 4 + quad) ^ (ur & 7);
                aU[tt] = *(const bf16x8*)&Ulds[b][ur * G2_BK + up * 8];
                int tr = wy * 64 + tt * 16 + l15;
                int tp = (ks * 4 + quad) ^ (tr & 7);
                bT[tt] = *(const bf16x8*)&Tlds[b][tr * G2_BK + tp * 8];
            }
            #pragma unroll
            for (int nt = 0; nt < 4; ++nt)
                #pragma unroll
                for (int mt = 0; mt < 4; ++mt)
                    acc[nt][mt] = __builtin_amdgcn_mfma_f32_16x16x32_bf16(
                        aU[nt], bT[mt], acc[nt][mt], 0, 0, 0);
        }
    }

    // epilogue: D row = outf offset (quad*4+r), col = token (l15)
    #pragma unroll
    for (int nt = 0; nt < 4; ++nt) {
        int n_base = n0 + wx * 64 + nt * 16 + quad * 4;
        #pragma unroll
        for (int mt = 0; mt < 4; ++mt) {
            int m = m0 + wy * 64 + mt * 16 + l15;
            float4 v;
            v.x = acc[nt][mt][0] + bv[nt].x;
            v.y = acc[nt][mt][1] + bv[nt].y;
            v.z = acc[nt][mt][2] + bv[nt].z;
            v.w = acc[nt][mt][3] + bv[nt].w;
            *(float4*)&out[(size_t)m * OUTF + n_base] = v;
        }
    }
}

extern "C" void kernel_launch(void* const* d_in, const int* in_sizes, int n_in,
                              void* d_out, int out_size, void* d_ws, size_t ws_size,
                              hipStream_t stream) {
    const float* x    = (const float*)d_in[0];
    const float* U    = (const float*)d_in[1];
    const float* V    = (const float*)d_in[2];
    const float* bias = (const float*)d_in[3];
    float* out = (float*)d_out;

    // ws layout: Vb (2MB) | Ub (2MB) | Tb (4MB)  => 8 MB total
    unsigned short* Vb = (unsigned short*)d_ws;
    unsigned short* Ub = Vb + (size_t)RANK * INF;
    unsigned short* Tb = Ub + (size_t)OUTF * RANK;

    const int nv = RANK * INF / 4;   // float4 elems in V
    const int nu = OUTF * RANK / 4;  // float4 elems in U
    cvt4<<<(nv + nu) / 256, 256, 0, stream>>>((const float4*)V, (ushort4*)Vb, nv,
                                              (const float4*)U, (ushort4*)Ub);
    gemm1<<<TOKENS / G1_BM, 512, 0, stream>>>(x, Vb, Tb);
    gemm2<<<dim3(OUTF / G2_BN, TOKENS / G2_BM), 256, 0, stream>>>(Tb, Ub, bias, out);
}